// Round 10
// baseline (1963.070 us; speedup 1.0000x reference)
//
#include <hip/hip_runtime.h>
#include <hip/hip_bf16.h>
#include <math.h>

constexpr int NP  = 32768;  // mesh points
constexpr int HH  = 8;      // heads

typedef short bf16x8 __attribute__((ext_vector_type(8)));
typedef float f32x4  __attribute__((ext_vector_type(4)));

__device__ __forceinline__ float gelu_f(float x) {
    return 0.5f * x * (1.0f + erff(x * 0.70710678118654752f));
}

__device__ __forceinline__ unsigned short f2bf(float x) {
    union { float f; unsigned u; } v; v.f = x;
    unsigned r = v.u + 0x7fffu + ((v.u >> 16) & 1u);
    return (unsigned short)(r >> 16);
}

// ---------------------------------------------------------------------------
// Weight prep: src [G][K][256] fp32 -> dst [G][256][K] bf16 (transposed)
// ---------------------------------------------------------------------------
__global__ __launch_bounds__(256) void transpose_bf16_k(
    const float* __restrict__ src, unsigned short* __restrict__ dst, int K)
{
    __shared__ float tile[32][33];
    int g = blockIdx.z;
    int k0 = blockIdx.x * 32, c0 = blockIdx.y * 32;
    int tx = threadIdx.x & 31, ty = threadIdx.x >> 5;
    const float* s = src + (size_t)g * K * 256;
    unsigned short* d = dst + (size_t)g * 256 * K;
    #pragma unroll
    for (int rr = 0; rr < 4; ++rr) {
        int r = ty + rr * 8;
        tile[r][tx] = s[(size_t)(k0 + r) * 256 + c0 + tx];
    }
    __syncthreads();
    #pragma unroll
    for (int rr = 0; rr < 4; ++rr) {
        int r = ty + rr * 8;
        d[(size_t)(c0 + r) * K + k0 + tx] = f2bf(tile[tx][r]);
    }
}

// Same, but scales row k by g[z*256+k] before rounding (LN-fold weights g.W)
__global__ __launch_bounds__(256) void transpose_scale_bf16_k(
    const float* __restrict__ src, const float* __restrict__ g,
    unsigned short* __restrict__ dst, int K)
{
    __shared__ float tile[32][33];
    int z = blockIdx.z;
    int k0 = blockIdx.x * 32, c0 = blockIdx.y * 32;
    int tx = threadIdx.x & 31, ty = threadIdx.x >> 5;
    const float* s = src + (size_t)z * K * 256;
    unsigned short* d = dst + (size_t)z * 256 * K;
    #pragma unroll
    for (int rr = 0; rr < 4; ++rr) {
        int r = ty + rr * 8;
        tile[r][tx] = s[(size_t)(k0 + r) * 256 + c0 + tx];
    }
    __syncthreads();
    float gs = g[z * 256 + k0 + tx];
    #pragma unroll
    for (int rr = 0; rr < 4; ++rr) {
        int r = ty + rr * 8;
        d[(size_t)(c0 + r) * K + k0 + tx] = f2bf(gs * tile[tx][r]);
    }
}

// c2[z][c] = sum_k g[z][k] W[z][k][c] ; c1[z][c] = sum_k b[z][k] W[z][k][c]
__global__ __launch_bounds__(256) void colsum_k(
    const float* __restrict__ W, const float* __restrict__ g,
    const float* __restrict__ b, float* __restrict__ c2, float* __restrict__ c1)
{
    int z = blockIdx.z, c = threadIdx.x;
    const float* Wz = W + (size_t)z * 65536;
    const float* gz = g + z * 256;
    const float* bz = b + z * 256;
    float s2 = 0.f, s1 = 0.f;
    for (int k = 0; k < 256; ++k) {
        float w = Wz[k * 256 + c];
        s2 += gz[k] * w;
        s1 += bz[k] * w;
    }
    c2[z * 256 + c] = s2;
    c1[z * 256 + c] = s1;
}

// ---------------------------------------------------------------------------
// MFMA GEMM, bf16 A-path (R10). A is pre-rounded bf16 [NP][K] (or generated,
// GENA). LN is folded into the epilogue (LNFOLD):
//   y = rstd*(t - mean*c2[c]) + (c1[c] + bias[c]),  t = a_bf16 @ (g.W)_bf16
// Epilogue writes fp32 (outF) and/or bf16 (outH) copies; RESID reads outF.
// A-staging is one uint4 load + swizzled LDS store per iter (was ~30 VALU
// insts of fp32 load + LN + cvt) — the R9 profile showed staging VALU
// dominating MFMA ~3:1.
// ---------------------------------------------------------------------------
template<bool GENA, bool LNFOLD, bool DOGELU, bool RESID, bool STATS, bool PERM>
__global__ __launch_bounds__(256) void gemm_bf(
    const unsigned short* __restrict__ Ah,
    const unsigned short* __restrict__ Wt,
    const float* __restrict__ bias, const float* __restrict__ bias2,
    float* __restrict__ outF, unsigned short* __restrict__ outH,
    const float* __restrict__ stats_in, float* __restrict__ stats_out,
    const float* __restrict__ c1v, const float* __restrict__ c2vec,
    const float* __restrict__ genx, const float* __restrict__ genw1,
    const float* __restrict__ genb1, int K)
{
    __shared__ __align__(16) unsigned short As[128 * 64];
    __shared__ __align__(16) unsigned short Bs[128 * 64];
    __shared__ float rmean[LNFOLD ? 128 : 1];
    __shared__ float rrstd[LNFOLD ? 128 : 1];
    __shared__ float w1s[GENA ? 1536 : 1];
    __shared__ float b1s[GENA ? 512 : 1];
    __shared__ float x3s[GENA ? 512 : 1];

    const int tid = threadIdx.x;
    const int rBase = blockIdx.x * 128, cBase = blockIdx.y * 128;

    if constexpr (GENA) {
        for (int i2 = tid; i2 < 1536; i2 += 256) w1s[i2] = genw1[i2];
        for (int i2 = tid; i2 < 512; i2 += 256) b1s[i2] = genb1[i2];
        if (tid < 128) {
            x3s[tid * 4 + 0] = genx[(size_t)(rBase + tid) * 3 + 0];
            x3s[tid * 4 + 1] = genx[(size_t)(rBase + tid) * 3 + 1];
            x3s[tid * 4 + 2] = genx[(size_t)(rBase + tid) * 3 + 2];
        }
        __syncthreads();
    }
    if constexpr (LNFOLD) {
        if (tid < 128) {
            const float* sp = stats_in + (size_t)(rBase + tid) * 8;
            float4 s0 = *(const float4*)sp;
            float4 s1 = *(const float4*)(sp + 4);
            float mean = (s0.x + s0.z + s1.x + s1.z) * (1.f / 256.f);
            float ex2  = (s0.y + s0.w + s1.y + s1.w) * (1.f / 256.f);
            rmean[tid] = mean;
            rrstd[tid] = rsqrtf(fmaxf(ex2 - mean * mean, 0.f) + 1e-5f);
        }
        __syncthreads();
    }

    f32x4 acc[4][4];
    #pragma unroll
    for (int i = 0; i < 4; ++i)
        #pragma unroll
        for (int j = 0; j < 4; ++j)
            acc[i][j] = (f32x4){0.f, 0.f, 0.f, 0.f};

    const int lane = tid & 63, wid = tid >> 6;
    const int wr = wid >> 1, wc = wid & 1;
    const int lrow = lane & 15, quad = lane >> 4;
    const int srow = tid >> 3;   // 0..31
    const int sch  = tid & 7;    // k-chunk of 8

    for (int kc = 0; kc < K; kc += 64) {
        // ---- stage A ----
        if constexpr (GENA) {
            #pragma unroll
            for (int it = 0; it < 4; ++it) {
                int row = srow + it * 32;
                float x0 = x3s[row * 4 + 0], x1 = x3s[row * 4 + 1], x2 = x3s[row * 4 + 2];
                unsigned short pk[8];
                #pragma unroll
                for (int j = 0; j < 8; ++j) {
                    int k = kc + sch * 8 + j;
                    float t = x0 * w1s[k] + x1 * w1s[512 + k] + x2 * w1s[1024 + k] + b1s[k];
                    pk[j] = f2bf(gelu_f(t));
                }
                *(uint4*)&As[row * 64 + ((sch ^ (row & 7)) << 3)] = *(uint4*)pk;
            }
        } else {
            #pragma unroll
            for (int it = 0; it < 4; ++it) {
                int row = srow + it * 32;
                uint4 av = *(const uint4*)(Ah + (size_t)(rBase + row) * K + kc + sch * 8);
                *(uint4*)&As[row * 64 + ((sch ^ (row & 7)) << 3)] = av;
            }
        }
        // ---- stage B ----
        #pragma unroll
        for (int it = 0; it < 4; ++it) {
            int n = srow + it * 32;
            uint4 wv_ = *(const uint4*)(Wt + (size_t)(cBase + n) * K + kc + sch * 8);
            *(uint4*)&Bs[n * 64 + ((sch ^ (n & 7)) << 3)] = wv_;
        }
        __syncthreads();
        #pragma unroll
        for (int ks = 0; ks < 2; ++ks) {
            bf16x8 af[4], bfr[4];
            #pragma unroll
            for (int t = 0; t < 4; ++t) {
                int row = wr * 64 + t * 16 + lrow;
                af[t] = *(bf16x8*)&As[row * 64 + (((ks * 4 + quad) ^ (row & 7)) << 3)];
                int n = wc * 64 + t * 16 + lrow;
                bfr[t] = *(bf16x8*)&Bs[n * 64 + (((ks * 4 + quad) ^ (n & 7)) << 3)];
            }
            #pragma unroll
            for (int ti = 0; ti < 4; ++ti)
                #pragma unroll
                for (int tj = 0; tj < 4; ++tj)
                    acc[ti][tj] = __builtin_amdgcn_mfma_f32_16x16x32_bf16(
                        af[ti], bfr[tj], acc[ti][tj], 0, 0, 0);
        }
        __syncthreads();
    }

    // ---- epilogue ----
    float c1b[4], c2r[4];
    #pragma unroll
    for (int tj = 0; tj < 4; ++tj) {
        int gcol = cBase + wc * 64 + tj * 16 + lrow;
        float b = bias[gcol];
        if (bias2) b += bias2[gcol];
        if constexpr (LNFOLD) {
            c1b[tj] = c1v[gcol] + b;
            c2r[tj] = c2vec[gcol];
        } else {
            c1b[tj] = b;
            c2r[tj] = 0.f;
        }
    }
    #pragma unroll
    for (int ti = 0; ti < 4; ++ti) {
        #pragma unroll
        for (int r = 0; r < 4; ++r) {
            int rib = wr * 64 + ti * 16 + quad * 4 + r;
            int grow = rBase + rib;
            float mean = 0.f, rstd = 1.f;
            if constexpr (LNFOLD) { mean = rmean[rib]; rstd = rrstd[rib]; }
            float vv[4];
            #pragma unroll
            for (int tj = 0; tj < 4; ++tj) {
                float t = acc[ti][tj][r];
                float v;
                if constexpr (LNFOLD) v = rstd * (t - mean * c2r[tj]) + c1b[tj];
                else                  v = t + c1b[tj];
                if constexpr (DOGELU) v = gelu_f(v);
                vv[tj] = v;
            }
            if constexpr (RESID) {
                #pragma unroll
                for (int tj = 0; tj < 4; ++tj) {
                    int gcol = cBase + wc * 64 + tj * 16 + lrow;
                    vv[tj] += outF[(size_t)grow * 256 + gcol];
                }
            }
            if constexpr (STATS) {
                float rs = vv[0] + vv[1] + vv[2] + vv[3];
                float rq = vv[0]*vv[0] + vv[1]*vv[1] + vv[2]*vv[2] + vv[3]*vv[3];
                #pragma unroll
                for (int m = 1; m < 16; m <<= 1) {
                    rs += __shfl_xor(rs, m);
                    rq += __shfl_xor(rq, m);
                }
                if (lrow == 0) {
                    stats_out[(size_t)grow * 8 + (blockIdx.y * 2 + wc) * 2 + 0] = rs;
                    stats_out[(size_t)grow * 8 + (blockIdx.y * 2 + wc) * 2 + 1] = rq;
                }
            }
            #pragma unroll
            for (int tj = 0; tj < 4; ++tj) {
                int gcol = cBase + wc * 64 + tj * 16 + lrow;
                if constexpr (PERM) {
                    outF[(size_t)(gcol >> 5) * NP * 32 + (size_t)grow * 32 + (gcol & 31)] = vv[tj];
                } else {
                    if (outF) outF[(size_t)grow * 256 + gcol] = vv[tj];
                    if (outH) outH[(size_t)grow * 256 + gcol] = f2bf(vv[tj]);
                }
            }
        }
    }
}

// ---------------------------------------------------------------------------
// kv5 (unchanged, working): wk in registers, deterministic partials.
// partials layout: [h][chunk][4224] = 128*32 kv + 128 sumexp
// ---------------------------------------------------------------------------
__global__ __launch_bounds__(512) void kv5_kernel(
    const float* __restrict__ xm2, const float* __restrict__ wk,
    const float* __restrict__ wv, const float* __restrict__ tk_arr,
    float* __restrict__ partials, int layer)
{
    __shared__ __align__(16) float smem[5120];
    float* xs  = smem;            // [64][32]
    float* vs  = smem + 2048;     // [64][32]
    float* wvs = smem + 4096;     // [32][32]
    float* red = smem;            // [512][9] alias

    const int tid = threadIdx.x;
    const int h = blockIdx.y;
    const int rowBase = blockIdx.x * 512;
    const int p  = tid >> 6;
    const int dg = tid & 63;

    float tk = fminf(fmaxf(tk_arr[layer * 8 + h], 0.1f), 2.0f);
    float invtk = 1.0f / tk;
    for (int i = tid; i < 1024; i += 512) wvs[i] = wv[i];

    float wkr0[32], wkr1[32];
    #pragma unroll
    for (int j = 0; j < 32; ++j) {
        float2 w2 = *(const float2*)(wk + j * 128 + dg * 2);
        wkr0[j] = w2.x; wkr1[j] = w2.y;
    }

    float acc0[32], acc1[32];
    #pragma unroll
    for (int c = 0; c < 32; ++c) { acc0[c] = 0.f; acc1[c] = 0.f; }
    float se0 = 0.f, se1 = 0.f;

    const float* src = xm2 + (size_t)h * NP * 32 + (size_t)rowBase * 32;
    const int lr = tid >> 3, lc = (tid & 7) * 4;

    for (int tile = 0; tile < 8; ++tile) {
        __syncthreads();
        *(float4*)&xs[lr * 32 + lc] =
            *(const float4*)(src + (size_t)(tile * 64 + lr) * 32 + lc);
        __syncthreads();
        {
            float a0 = 0.f, a1 = 0.f, a2 = 0.f, a3 = 0.f;
            #pragma unroll
            for (int j = 0; j < 32; ++j) {
                float xv = xs[lr * 32 + j];
                float4 w4 = *(const float4*)&wvs[j * 32 + lc];
                a0 += xv * w4.x; a1 += xv * w4.y; a2 += xv * w4.z; a3 += xv * w4.w;
            }
            float4 o; o.x = a0; o.y = a1; o.z = a2; o.w = a3;
            *(float4*)&vs[lr * 32 + lc] = o;
        }
        __syncthreads();
        #pragma unroll 1
        for (int t = 0; t < 8; ++t) {
            int n = p * 8 + t;
            float l0 = 0.f, l1 = 0.f;
            #pragma unroll
            for (int j4 = 0; j4 < 8; ++j4) {
                float4 x4 = *(const float4*)&xs[n * 32 + j4 * 4];
                l0 += x4.x * wkr0[j4 * 4 + 0] + x4.y * wkr0[j4 * 4 + 1]
                    + x4.z * wkr0[j4 * 4 + 2] + x4.w * wkr0[j4 * 4 + 3];
                l1 += x4.x * wkr1[j4 * 4 + 0] + x4.y * wkr1[j4 * 4 + 1]
                    + x4.z * wkr1[j4 * 4 + 2] + x4.w * wkr1[j4 * 4 + 3];
            }
            float e0 = __expf(fminf(fmaxf(l0 * invtk, -60.f), 60.f));
            float e1 = __expf(fminf(fmaxf(l1 * invtk, -60.f), 60.f));
            se0 += e0; se1 += e1;
            #pragma unroll
            for (int cc = 0; cc < 8; ++cc) {
                float4 v4 = *(const float4*)&vs[n * 32 + cc * 4];
                acc0[cc*4+0] += e0 * v4.x; acc0[cc*4+1] += e0 * v4.y;
                acc0[cc*4+2] += e0 * v4.z; acc0[cc*4+3] += e0 * v4.w;
                acc1[cc*4+0] += e1 * v4.x; acc1[cc*4+1] += e1 * v4.y;
                acc1[cc*4+2] += e1 * v4.z; acc1[cc*4+3] += e1 * v4.w;
            }
        }
    }

    float* outp = partials + ((size_t)h * 64 + blockIdx.x) * 4224;
    #pragma unroll
    for (int cc = 0; cc < 8; ++cc) {
        __syncthreads();
        #pragma unroll
        for (int ci = 0; ci < 4; ++ci) {
            red[tid * 9 + ci]     = acc0[cc * 4 + ci];
            red[tid * 9 + 4 + ci] = acc1[cc * 4 + ci];
        }
        __syncthreads();
        int d = tid >> 2, ci = tid & 3;
        float s = 0.f;
        #pragma unroll
        for (int pp = 0; pp < 8; ++pp)
            s += red[(pp * 64 + (d >> 1)) * 9 + (d & 1) * 4 + ci];
        outp[d * 32 + cc * 4 + ci] = s;
    }
    __syncthreads();
    red[tid * 9 + 0] = se0;
    red[tid * 9 + 1] = se1;
    __syncthreads();
    if (tid < 128) {
        int d = tid;
        float s = 0.f;
        #pragma unroll
        for (int pp = 0; pp < 8; ++pp)
            s += red[(pp * 64 + (d >> 1)) * 9 + (d & 1)];
        outp[4096 + d] = s;
    }
}

__global__ __launch_bounds__(256) void kv_reduce_kernel(
    const float* __restrict__ partials, float* __restrict__ kvU,
    float* __restrict__ sumexp)
{
    int gid = blockIdx.x * 256 + threadIdx.x;
    if (gid >= 8 * 4224) return;
    int h = gid / 4224, idx = gid % 4224;
    const float* base = partials + (size_t)h * 64 * 4224 + idx;
    float s = 0.f;
    #pragma unroll 8
    for (int c = 0; c < 64; ++c) s += base[(size_t)c * 4224];
    if (idx < 4096) kvU[(size_t)h * 4096 + idx] = s;
    else sumexp[h * 128 + (idx - 4096)] = s;
}

// ---------------------------------------------------------------------------
// qkv3 (R10: writes bf16 Dt directly — its only consumer is out_w1's bf16
// A-stage, so values are identical to the old fp32-then-round path).
// ---------------------------------------------------------------------------
__global__ __launch_bounds__(256) void qkv3_kernel(
    const float* __restrict__ xm2, const float* __restrict__ wq,
    const float* __restrict__ tq_arr,
    const float* __restrict__ kvU, const float* __restrict__ sumexp,
    unsigned short* __restrict__ outH, int layer)
{
    __shared__ __align__(16) float xsw[4096];
    __shared__ __align__(16) float wqs[4096];
    __shared__ __align__(16) float kvs[4096];
    __shared__ float ises[128];

    const int tid = threadIdx.x;
    const int h = blockIdx.y;
    const int rowBase = blockIdx.x * 128;
    const int rt = tid >> 4;
    const int dt = tid & 15;

    float tq = fminf(fmaxf(tq_arr[layer * 8 + h], 0.1f), 2.0f);
    float invtq = 1.0f / tq;

    if (tid < 128) ises[tid] = 1.0f / sumexp[h * 128 + tid];
    #pragma unroll
    for (int it = 0; it < 4; ++it) {
        int i4 = tid + it * 256;
        int k = i4 >> 5, c4 = i4 & 31;
        float4 v = *(const float4*)(wq + (size_t)k * 128 + c4 * 4);
        int c4s = c4 ^ ((c4 >> 1) & 7);
        *(float4*)&wqs[k * 128 + c4s * 4] = v;
    }
    {
        const float* kvsrc = kvU + (size_t)h * 4096;
        #pragma unroll
        for (int it = 0; it < 4; ++it) {
            int i4 = tid + it * 256;
            int d = i4 >> 3, c4 = i4 & 7;
            float4 v = *(const float4*)(kvsrc + (size_t)d * 32 + c4 * 4);
            int c4s = c4 ^ ((d >> 3) & 7);
            *(float4*)&kvs[d * 32 + c4s * 4] = v;
        }
    }
    {
        const float* src = xm2 + (size_t)h * NP * 32 + (size_t)rowBase * 32;
        #pragma unroll
        for (int it = 0; it < 4; ++it) {
            int s = tid + it * 256;
            int r = s >> 3, j4 = s & 7;
            float4 v = *(const float4*)(src + (size_t)r * 32 + j4 * 4);
            *(float4*)&xsw[r * 32 + ((j4 ^ ((r >> 3) & 7)) << 2)] = v;
        }
    }
    __syncthreads();

    const int swr = rt & 7;
    const int swd = dt & 7;

    float l[8][8];
    #pragma unroll
    for (int i = 0; i < 8; ++i)
        #pragma unroll
        for (int jd = 0; jd < 8; ++jd) l[i][jd] = 0.f;

    const int cA = (dt * 2)     ^ swd;
    const int cB = (dt * 2 + 1) ^ swd;
    #pragma unroll
    for (int j4 = 0; j4 < 8; ++j4) {
        float4 xv[8];
        #pragma unroll
        for (int i = 0; i < 8; ++i)
            xv[i] = *(const float4*)&xsw[(rt * 8 + i) * 32 + ((j4 ^ swr) << 2)];
        #pragma unroll
        for (int kk = 0; kk < 4; ++kk) {
            int k = j4 * 4 + kk;
            float4 wa = *(const float4*)&wqs[k * 128 + cA * 4];
            float4 wb = *(const float4*)&wqs[k * 128 + cB * 4];
            #pragma unroll
            for (int i = 0; i < 8; ++i) {
                float xx = (kk == 0) ? xv[i].x : (kk == 1) ? xv[i].y
                         : (kk == 2) ? xv[i].z : xv[i].w;
                l[i][0] += xx * wa.x; l[i][1] += xx * wa.y;
                l[i][2] += xx * wa.z; l[i][3] += xx * wa.w;
                l[i][4] += xx * wb.x; l[i][5] += xx * wb.y;
                l[i][6] += xx * wb.z; l[i][7] += xx * wb.w;
            }
        }
    }

    float isr[8];
    #pragma unroll
    for (int jd = 0; jd < 8; ++jd) isr[jd] = ises[dt * 8 + jd];
    #pragma unroll
    for (int i = 0; i < 8; ++i) {
        float m = l[i][0];
        #pragma unroll
        for (int jd = 1; jd < 8; ++jd) m = fmaxf(m, l[i][jd]);
        m = fmaxf(m, __shfl_xor(m, 1));
        m = fmaxf(m, __shfl_xor(m, 2));
        m = fmaxf(m, __shfl_xor(m, 4));
        m = fmaxf(m, __shfl_xor(m, 8));
        float s = 0.f;
        #pragma unroll
        for (int jd = 0; jd < 8; ++jd) {
            float e = __expf((l[i][jd] - m) * invtq);
            l[i][jd] = e;
            s += e;
        }
        s += __shfl_xor(s, 1);
        s += __shfl_xor(s, 2);
        s += __shfl_xor(s, 4);
        s += __shfl_xor(s, 8);
        float inv = 1.0f / s;
        #pragma unroll
        for (int jd = 0; jd < 8; ++jd) l[i][jd] *= inv * isr[jd];
    }

    const int b0 = dt & 1, b1 = (dt >> 1) & 1, b2 = (dt >> 2) & 1, b3 = (dt >> 3) & 1;
    #pragma unroll
    for (int chunk = 0; chunk < 4; ++chunk) {
        float o[8][8];
        #pragma unroll
        for (int i = 0; i < 8; ++i)
            #pragma unroll
            for (int c = 0; c < 8; ++c) o[i][c] = 0.f;
        const int kA = (chunk * 2)     ^ swd;
        const int kB = (chunk * 2 + 1) ^ swd;
        #pragma unroll
        for (int jd = 0; jd < 8; ++jd) {
            int d = dt * 8 + jd;
            float4 ka = *(const float4*)&kvs[d * 32 + kA * 4];
            float4 kb = *(const float4*)&kvs[d * 32 + kB * 4];
            #pragma unroll
            for (int i = 0; i < 8; ++i) {
                float p = l[i][jd];
                o[i][0] += p * ka.x; o[i][1] += p * ka.y;
                o[i][2] += p * ka.z; o[i][3] += p * ka.w;
                o[i][4] += p * kb.x; o[i][5] += p * kb.y;
                o[i][6] += p * kb.z; o[i][7] += p * kb.w;
            }
        }
        float t1[4][8];
        #pragma unroll
        for (int i = 0; i < 4; ++i)
            #pragma unroll
            for (int c = 0; c < 8; ++c) {
                float keep = b0 ? o[i + 4][c] : o[i][c];
                float send = b0 ? o[i][c] : o[i + 4][c];
                t1[i][c] = keep + __shfl_xor(send, 1);
            }
        float t2[2][8];
        #pragma unroll
        for (int i = 0; i < 2; ++i)
            #pragma unroll
            for (int c = 0; c < 8; ++c) {
                float keep = b1 ? t1[i + 2][c] : t1[i][c];
                float send = b1 ? t1[i][c] : t1[i + 2][c];
                t2[i][c] = keep + __shfl_xor(send, 2);
            }
        float t3[2][4];
        #pragma unroll
        for (int i = 0; i < 2; ++i)
            #pragma unroll
            for (int c = 0; c < 4; ++c) {
                float keep = b2 ? t2[i][c + 4] : t2[i][c];
                float send = b2 ? t2[i][c] : t2[i][c + 4];
                t3[i][c] = keep + __shfl_xor(send, 4);
            }
        float t4[4];
        #pragma unroll
        for (int c = 0; c < 4; ++c) {
            float keep = b3 ? t3[1][c] : t3[0][c];
            float send = b3 ? t3[0][c] : t3[1][c];
            t4[c] = keep + __shfl_xor(send, 8);
        }
        int row = rt * 8 + b0 * 4 + b1 * 2 + b3;
        unsigned short hh[4];
        hh[0] = f2bf(t4[0]); hh[1] = f2bf(t4[1]);
        hh[2] = f2bf(t4[2]); hh[3] = f2bf(t4[3]);
        *(uint2*)(outH + (size_t)(rowBase + row) * 256 + h * 32 + chunk * 8 + b2 * 4)
            = *(uint2*)hh;
    }
}

// ---------------------------------------------------------------------------
// head: out[n] = LN(fx[n]; ln3) . head_w + head_b
// ---------------------------------------------------------------------------
__global__ __launch_bounds__(256) void head_kernel(
    const float* __restrict__ fx, const float* __restrict__ g, const float* __restrict__ b,
    const float* __restrict__ hw, const float* __restrict__ hb, float* __restrict__ out)
{
    int lane = threadIdx.x & 63;
    int row = blockIdx.x * 4 + (threadIdx.x >> 6);
    float4 v = *(const float4*)(fx + (size_t)row * 256 + lane * 4);
    float s1 = v.x + v.y + v.z + v.w;
    float s2 = v.x * v.x + v.y * v.y + v.z * v.z + v.w * v.w;
    #pragma unroll
    for (int m = 1; m < 64; m <<= 1) { s1 += __shfl_xor(s1, m); s2 += __shfl_xor(s2, m); }
    float mean = s1 * 0.00390625f;
    float rstd = rsqrtf(fmaxf(s2 * 0.00390625f - mean * mean, 0.f) + 1e-5f);
    float4 gg = *(const float4*)(g + lane * 4);
    float4 bb = *(const float4*)(b + lane * 4);
    float4 w4 = *(const float4*)(hw + lane * 4);
    float d = ((v.x - mean) * rstd * gg.x + bb.x) * w4.x
            + ((v.y - mean) * rstd * gg.y + bb.y) * w4.y
            + ((v.z - mean) * rstd * gg.z + bb.z) * w4.z
            + ((v.w - mean) * rstd * gg.w + bb.w) * w4.w;
    #pragma unroll
    for (int m = 1; m < 64; m <<= 1) d += __shfl_xor(d, m);
    if (lane == 0) out[row] = d + hb[0];
}

extern "C" void kernel_launch(void* const* d_in, const int* in_sizes, int n_in,
                              void* d_out, int out_size, void* d_ws, size_t ws_size,
                              hipStream_t stream)
{
    const float* x      = (const float*)d_in[0];
    const float* pre_w1 = (const float*)d_in[1];
    const float* pre_b1 = (const float*)d_in[2];
    const float* pre_w2 = (const float*)d_in[3];
    const float* pre_b2 = (const float*)d_in[4];
    const float* ph     = (const float*)d_in[5];
    const float* ln1_g  = (const float*)d_in[6];
    const float* ln1_b  = (const float*)d_in[7];
    const float* inp_w  = (const float*)d_in[8];
    const float* inp_b  = (const float*)d_in[9];
    const float* temp_q = (const float*)d_in[10];
    const float* temp_k = (const float*)d_in[11];
    const float* wq     = (const float*)d_in[12];
    const float* wk     = (const float*)d_in[13];
    const float* wv     = (const float*)d_in[14];
    const float* out_w1 = (const float*)d_in[15];
    const float* out_b1 = (const float*)d_in[16];
    const float* out_w2 = (const float*)d_in[17];
    const float* out_b2 = (const float*)d_in[18];
    const float* ln2_g  = (const float*)d_in[19];
    const float* ln2_b  = (const float*)d_in[20];
    const float* mlp_w1 = (const float*)d_in[21];
    const float* mlp_b1 = (const float*)d_in[22];
    const float* mlp_w2 = (const float*)d_in[23];
    const float* mlp_b2 = (const float*)d_in[24];
    const float* ln3_g  = (const float*)d_in[25];
    const float* ln3_b  = (const float*)d_in[26];
    const float* head_w = (const float*)d_in[27];
    const float* head_b = (const float*)d_in[28];
    float* out = (float*)d_out;

    // ws layout: fx f32 | C f32 (xm2) | fxh bf16 | DtH bf16 | ChH bf16 |
    //            stats | kvU | se | c-vectors | wtPre | wtL
    float* fx = (float*)d_ws;
    float* C  = fx + (size_t)NP * 256;
    unsigned short* fxh = (unsigned short*)(C + (size_t)NP * 256);
    unsigned short* DtH = fxh + (size_t)NP * 256;
    unsigned short* ChH = DtH + (size_t)NP * 256;
    float* st = (float*)(ChH + (size_t)NP * 256);
    float* kv = st + (size_t)NP * 8;
    float* se = kv + 8 * 4096;
    float* c1i = se + 8 * 128;
    float* c2i = c1i + 1280;
    float* c1m = c2i + 1280;
    float* c2m = c1m + 1280;
    unsigned short* wtPre = (unsigned short*)(c2m + 1280);
    unsigned short* wtL   = wtPre + 256 * 512;   // 25 x [256][256]
    float* partials = (float*)ChH;               // alias (ChH dead during kv)

    unsigned short* wtIn = wtL;
    unsigned short* wtO1 = wtL +  5 * 65536;
    unsigned short* wtO2 = wtL + 10 * 65536;
    unsigned short* wtM1 = wtL + 15 * 65536;
    unsigned short* wtM2 = wtL + 20 * 65536;

    dim3 bt(256);

    // weight prep
    transpose_bf16_k<<<dim3(16, 8, 1), bt, 0, stream>>>(pre_w2, wtPre, 512);
    transpose_scale_bf16_k<<<dim3(8, 8, 5), bt, 0, stream>>>(inp_w,  ln1_g, wtIn, 256);
    transpose_bf16_k<<<dim3(8, 8, 5), bt, 0, stream>>>(out_w1, wtO1, 256);
    transpose_bf16_k<<<dim3(8, 8, 5), bt, 0, stream>>>(out_w2, wtO2, 256);
    transpose_scale_bf16_k<<<dim3(8, 8, 5), bt, 0, stream>>>(mlp_w1, ln2_g, wtM1, 256);
    transpose_bf16_k<<<dim3(8, 8, 5), bt, 0, stream>>>(mlp_w2, wtM2, 256);
    colsum_k<<<dim3(1, 1, 5), bt, 0, stream>>>(inp_w,  ln1_g, ln1_b, c2i, c1i);
    colsum_k<<<dim3(1, 1, 5), bt, 0, stream>>>(mlp_w1, ln2_g, ln2_b, c2m, c1m);

    dim3 gg(256, 2);

    // preprocess: fx/fxh = GELU(x@pre_w1+pre_b1)@pre_w2 + pre_b2 + ph (+stats)
    gemm_bf<true, false, false, false, true, false><<<gg, bt, 0, stream>>>(
        nullptr, wtPre, pre_b2, ph, fx, fxh, nullptr, st, nullptr, nullptr,
        x, pre_w1, pre_b1, 512);

    for (int i = 0; i < 5; ++i) {
        // xm2 = perm( LN(fx;ln1) @ inp_w + inp_b )   [LN folded]
        gemm_bf<false, true, false, false, false, true><<<gg, bt, 0, stream>>>(
            fxh, wtIn + (size_t)i * 65536, inp_b + i * 256, nullptr, C, nullptr,
            st, nullptr, c1i + i * 256, c2i + i * 256,
            nullptr, nullptr, nullptr, 256);
        // kv partials + reduce
        kv5_kernel<<<dim3(64, 8), dim3(512), 0, stream>>>(
            C, wk + (size_t)i * 4096, wv + (size_t)i * 1024, temp_k, partials, i);
        kv_reduce_kernel<<<dim3(132), bt, 0, stream>>>(partials, kv, se);
        // qkv -> DtH bf16
        qkv3_kernel<<<dim3(256, 8), bt, 0, stream>>>(
            C, wq + (size_t)i * 4096, temp_q, kv, se, DtH, i);
        // ChH = bf16( GELU(Dt @ out_w1 + out_b1) )
        gemm_bf<false, false, true, false, false, false><<<gg, bt, 0, stream>>>(
            DtH, wtO1 + (size_t)i * 65536, out_b1 + i * 256, nullptr, nullptr, ChH,
            nullptr, nullptr, nullptr, nullptr, nullptr, nullptr, nullptr, 256);
        // fx += Ch @ out_w2 + out_b2   (+stats, +fxh)
        gemm_bf<false, false, false, true, true, false><<<gg, bt, 0, stream>>>(
            ChH, wtO2 + (size_t)i * 65536, out_b2 + i * 256, nullptr, fx, fxh,
            nullptr, st, nullptr, nullptr, nullptr, nullptr, nullptr, 256);
        // DtH = bf16( GELU( LN(fx;ln2) @ mlp_w1 + mlp_b1 ) )   [LN folded]
        gemm_bf<false, true, true, false, false, false><<<gg, bt, 0, stream>>>(
            fxh, wtM1 + (size_t)i * 65536, mlp_b1 + i * 256, nullptr, nullptr, DtH,
            st, nullptr, c1m + i * 256, c2m + i * 256,
            nullptr, nullptr, nullptr, 256);
        // fx += Dt @ mlp_w2 + mlp_b2  (+stats, +fxh)
        gemm_bf<false, false, false, true, true, false><<<gg, bt, 0, stream>>>(
            DtH, wtM2 + (size_t)i * 65536, mlp_b2 + i * 256, nullptr, fx, fxh,
            nullptr, st, nullptr, nullptr, nullptr, nullptr, nullptr, 256);
    }
    head_kernel<<<dim3(NP / 4), bt, 0, stream>>>(fx, ln3_g, ln3_b, head_w, head_b, out);
}

// Round 11
// 1647.945 us; speedup vs baseline: 1.1912x; 1.1912x over previous
//
#include <hip/hip_runtime.h>
#include <hip/hip_bf16.h>
#include <math.h>

constexpr int NP  = 32768;  // mesh points
constexpr int HH  = 8;      // heads

typedef short bf16x8 __attribute__((ext_vector_type(8)));
typedef float f32x4  __attribute__((ext_vector_type(4)));

__device__ __forceinline__ float gelu_f(float x) {
    return 0.5f * x * (1.0f + erff(x * 0.70710678118654752f));
}

__device__ __forceinline__ unsigned short f2bf(float x) {
    union { float f; unsigned u; } v; v.f = x;
    unsigned r = v.u + 0x7fffu + ((v.u >> 16) & 1u);
    return (unsigned short)(r >> 16);
}

// ---------------------------------------------------------------------------
// Weight prep: src [G][K][256] fp32 -> dst [G][256][K] bf16 (transposed)
// ---------------------------------------------------------------------------
__global__ __launch_bounds__(256) void transpose_bf16_k(
    const float* __restrict__ src, unsigned short* __restrict__ dst, int K)
{
    __shared__ float tile[32][33];
    int g = blockIdx.z;
    int k0 = blockIdx.x * 32, c0 = blockIdx.y * 32;
    int tx = threadIdx.x & 31, ty = threadIdx.x >> 5;
    const float* s = src + (size_t)g * K * 256;
    unsigned short* d = dst + (size_t)g * 256 * K;
    #pragma unroll
    for (int rr = 0; rr < 4; ++rr) {
        int r = ty + rr * 8;
        tile[r][tx] = s[(size_t)(k0 + r) * 256 + c0 + tx];
    }
    __syncthreads();
    #pragma unroll
    for (int rr = 0; rr < 4; ++rr) {
        int r = ty + rr * 8;
        d[(size_t)(c0 + r) * K + k0 + tx] = f2bf(tile[tx][r]);
    }
}

// Same, but scales row k by g[z*256+k] before rounding (LN-fold weights g.W)
__global__ __launch_bounds__(256) void transpose_scale_bf16_k(
    const float* __restrict__ src, const float* __restrict__ g,
    unsigned short* __restrict__ dst, int K)
{
    __shared__ float tile[32][33];
    int z = blockIdx.z;
    int k0 = blockIdx.x * 32, c0 = blockIdx.y * 32;
    int tx = threadIdx.x & 31, ty = threadIdx.x >> 5;
    const float* s = src + (size_t)z * K * 256;
    unsigned short* d = dst + (size_t)z * 256 * K;
    #pragma unroll
    for (int rr = 0; rr < 4; ++rr) {
        int r = ty + rr * 8;
        tile[r][tx] = s[(size_t)(k0 + r) * 256 + c0 + tx];
    }
    __syncthreads();
    float gs = g[z * 256 + k0 + tx];
    #pragma unroll
    for (int rr = 0; rr < 4; ++rr) {
        int r = ty + rr * 8;
        d[(size_t)(c0 + r) * K + k0 + tx] = f2bf(gs * tile[tx][r]);
    }
}

// c2[z][c] = sum_k g[z][k] W[z][k][c] ; c1[z][c] = sum_k b[z][k] W[z][k][c]
__global__ __launch_bounds__(256) void colsum_k(
    const float* __restrict__ W, const float* __restrict__ g,
    const float* __restrict__ b, float* __restrict__ c2, float* __restrict__ c1)
{
    int z = blockIdx.z, c = threadIdx.x;
    const float* Wz = W + (size_t)z * 65536;
    const float* gz = g + z * 256;
    const float* bz = b + z * 256;
    float s2 = 0.f, s1 = 0.f;
    for (int k = 0; k < 256; ++k) {
        float w = Wz[k * 256 + c];
        s2 += gz[k] * w;
        s1 += bz[k] * w;
    }
    c2[z * 256 + c] = s2;
    c1[z * 256 + c] = s1;
}

// ---------------------------------------------------------------------------
// MFMA GEMM, bf16/fp32 A-path (R11). A sources:
//   GENA: generated GELU(x@w1+b1); AF32: fp32 A, f2bf on stage (no LN);
//   else: pre-rounded bf16 A (one uint4 load per iter).
// LNFOLD epilogue: y = rstd*(t - mean*c2[c]) + (c1[c]+bias[c]).
// Epilogue writes fp32 (outF) and/or bf16 (outH); RESID reads outF.
// ---------------------------------------------------------------------------
template<bool GENA, bool AF32, bool LNFOLD, bool DOGELU, bool RESID, bool STATS, bool PERM>
__global__ __launch_bounds__(256) void gemm_bf(
    const unsigned short* __restrict__ Ah, const float* __restrict__ Af,
    const unsigned short* __restrict__ Wt,
    const float* __restrict__ bias, const float* __restrict__ bias2,
    float* __restrict__ outF, unsigned short* __restrict__ outH,
    const float* __restrict__ stats_in, float* __restrict__ stats_out,
    const float* __restrict__ c1v, const float* __restrict__ c2vec,
    const float* __restrict__ genx, const float* __restrict__ genw1,
    const float* __restrict__ genb1, int K)
{
    __shared__ __align__(16) unsigned short As[128 * 64];
    __shared__ __align__(16) unsigned short Bs[128 * 64];
    __shared__ float rmean[LNFOLD ? 128 : 1];
    __shared__ float rrstd[LNFOLD ? 128 : 1];
    __shared__ float w1s[GENA ? 1536 : 1];
    __shared__ float b1s[GENA ? 512 : 1];
    __shared__ float x3s[GENA ? 512 : 1];

    const int tid = threadIdx.x;
    const int rBase = blockIdx.x * 128, cBase = blockIdx.y * 128;

    if constexpr (GENA) {
        for (int i2 = tid; i2 < 1536; i2 += 256) w1s[i2] = genw1[i2];
        for (int i2 = tid; i2 < 512; i2 += 256) b1s[i2] = genb1[i2];
        if (tid < 128) {
            x3s[tid * 4 + 0] = genx[(size_t)(rBase + tid) * 3 + 0];
            x3s[tid * 4 + 1] = genx[(size_t)(rBase + tid) * 3 + 1];
            x3s[tid * 4 + 2] = genx[(size_t)(rBase + tid) * 3 + 2];
        }
        __syncthreads();
    }
    if constexpr (LNFOLD) {
        if (tid < 128) {
            const float* sp = stats_in + (size_t)(rBase + tid) * 8;
            float4 s0 = *(const float4*)sp;
            float4 s1 = *(const float4*)(sp + 4);
            float mean = (s0.x + s0.z + s1.x + s1.z) * (1.f / 256.f);
            float ex2  = (s0.y + s0.w + s1.y + s1.w) * (1.f / 256.f);
            rmean[tid] = mean;
            rrstd[tid] = rsqrtf(fmaxf(ex2 - mean * mean, 0.f) + 1e-5f);
        }
        __syncthreads();
    }

    f32x4 acc[4][4];
    #pragma unroll
    for (int i = 0; i < 4; ++i)
        #pragma unroll
        for (int j = 0; j < 4; ++j)
            acc[i][j] = (f32x4){0.f, 0.f, 0.f, 0.f};

    const int lane = tid & 63, wid = tid >> 6;
    const int wr = wid >> 1, wc = wid & 1;
    const int lrow = lane & 15, quad = lane >> 4;
    const int srow = tid >> 3;   // 0..31
    const int sch  = tid & 7;    // k-chunk of 8

    for (int kc = 0; kc < K; kc += 64) {
        // ---- stage A ----
        if constexpr (GENA) {
            #pragma unroll
            for (int it = 0; it < 4; ++it) {
                int row = srow + it * 32;
                float x0 = x3s[row * 4 + 0], x1 = x3s[row * 4 + 1], x2 = x3s[row * 4 + 2];
                unsigned short pk[8];
                #pragma unroll
                for (int j = 0; j < 8; ++j) {
                    int k = kc + sch * 8 + j;
                    float t = x0 * w1s[k] + x1 * w1s[512 + k] + x2 * w1s[1024 + k] + b1s[k];
                    pk[j] = f2bf(gelu_f(t));
                }
                *(uint4*)&As[row * 64 + ((sch ^ (row & 7)) << 3)] = *(uint4*)pk;
            }
        } else if constexpr (AF32) {
            #pragma unroll
            for (int it = 0; it < 4; ++it) {
                int row = srow + it * 32;
                const float* ap = Af + (size_t)(rBase + row) * K + kc + sch * 8;
                float4 a0 = *(const float4*)ap;
                float4 a1 = *(const float4*)(ap + 4);
                unsigned short pk[8];
                pk[0] = f2bf(a0.x); pk[1] = f2bf(a0.y); pk[2] = f2bf(a0.z); pk[3] = f2bf(a0.w);
                pk[4] = f2bf(a1.x); pk[5] = f2bf(a1.y); pk[6] = f2bf(a1.z); pk[7] = f2bf(a1.w);
                *(uint4*)&As[row * 64 + ((sch ^ (row & 7)) << 3)] = *(uint4*)pk;
            }
        } else {
            #pragma unroll
            for (int it = 0; it < 4; ++it) {
                int row = srow + it * 32;
                uint4 av = *(const uint4*)(Ah + (size_t)(rBase + row) * K + kc + sch * 8);
                *(uint4*)&As[row * 64 + ((sch ^ (row & 7)) << 3)] = av;
            }
        }
        // ---- stage B ----
        #pragma unroll
        for (int it = 0; it < 4; ++it) {
            int n = srow + it * 32;
            uint4 wv_ = *(const uint4*)(Wt + (size_t)(cBase + n) * K + kc + sch * 8);
            *(uint4*)&Bs[n * 64 + ((sch ^ (n & 7)) << 3)] = wv_;
        }
        __syncthreads();
        #pragma unroll
        for (int ks = 0; ks < 2; ++ks) {
            bf16x8 af[4], bfr[4];
            #pragma unroll
            for (int t = 0; t < 4; ++t) {
                int row = wr * 64 + t * 16 + lrow;
                af[t] = *(bf16x8*)&As[row * 64 + (((ks * 4 + quad) ^ (row & 7)) << 3)];
                int n = wc * 64 + t * 16 + lrow;
                bfr[t] = *(bf16x8*)&Bs[n * 64 + (((ks * 4 + quad) ^ (n & 7)) << 3)];
            }
            #pragma unroll
            for (int ti = 0; ti < 4; ++ti)
                #pragma unroll
                for (int tj = 0; tj < 4; ++tj)
                    acc[ti][tj] = __builtin_amdgcn_mfma_f32_16x16x32_bf16(
                        af[ti], bfr[tj], acc[ti][tj], 0, 0, 0);
        }
        __syncthreads();
    }

    // ---- epilogue ----
    float c1b[4], c2r[4];
    #pragma unroll
    for (int tj = 0; tj < 4; ++tj) {
        int gcol = cBase + wc * 64 + tj * 16 + lrow;
        float b = bias[gcol];
        if (bias2) b += bias2[gcol];
        if constexpr (LNFOLD) {
            c1b[tj] = c1v[gcol] + b;
            c2r[tj] = c2vec[gcol];
        } else {
            c1b[tj] = b;
            c2r[tj] = 0.f;
        }
    }
    #pragma unroll
    for (int ti = 0; ti < 4; ++ti) {
        #pragma unroll
        for (int r = 0; r < 4; ++r) {
            int rib = wr * 64 + ti * 16 + quad * 4 + r;
            int grow = rBase + rib;
            float mean = 0.f, rstd = 1.f;
            if constexpr (LNFOLD) { mean = rmean[rib]; rstd = rrstd[rib]; }
            float vv[4];
            #pragma unroll
            for (int tj = 0; tj < 4; ++tj) {
                float t = acc[ti][tj][r];
                float v;
                if constexpr (LNFOLD) v = rstd * (t - mean * c2r[tj]) + c1b[tj];
                else                  v = t + c1b[tj];
                if constexpr (DOGELU) v = gelu_f(v);
                vv[tj] = v;
            }
            if constexpr (RESID) {
                #pragma unroll
                for (int tj = 0; tj < 4; ++tj) {
                    int gcol = cBase + wc * 64 + tj * 16 + lrow;
                    vv[tj] += outF[(size_t)grow * 256 + gcol];
                }
            }
            if constexpr (STATS) {
                float rs = vv[0] + vv[1] + vv[2] + vv[3];
                float rq = vv[0]*vv[0] + vv[1]*vv[1] + vv[2]*vv[2] + vv[3]*vv[3];
                #pragma unroll
                for (int m = 1; m < 16; m <<= 1) {
                    rs += __shfl_xor(rs, m);
                    rq += __shfl_xor(rq, m);
                }
                if (lrow == 0) {
                    stats_out[(size_t)grow * 8 + (blockIdx.y * 2 + wc) * 2 + 0] = rs;
                    stats_out[(size_t)grow * 8 + (blockIdx.y * 2 + wc) * 2 + 1] = rq;
                }
            }
            #pragma unroll
            for (int tj = 0; tj < 4; ++tj) {
                int gcol = cBase + wc * 64 + tj * 16 + lrow;
                if constexpr (PERM) {
                    outF[(size_t)(gcol >> 5) * NP * 32 + (size_t)grow * 32 + (gcol & 31)] = vv[tj];
                } else {
                    if (outF) outF[(size_t)grow * 256 + gcol] = vv[tj];
                    if (outH) outH[(size_t)grow * 256 + gcol] = f2bf(vv[tj]);
                }
            }
        }
    }
}

// ---------------------------------------------------------------------------
// kv5 (unchanged, working): wk in registers, deterministic partials.
// partials layout: [h][chunk][4224] = 128*32 kv + 128 sumexp
// ---------------------------------------------------------------------------
__global__ __launch_bounds__(512) void kv5_kernel(
    const float* __restrict__ xm2, const float* __restrict__ wk,
    const float* __restrict__ wv, const float* __restrict__ tk_arr,
    float* __restrict__ partials, int layer)
{
    __shared__ __align__(16) float smem[5120];
    float* xs  = smem;            // [64][32]
    float* vs  = smem + 2048;     // [64][32]
    float* wvs = smem + 4096;     // [32][32]
    float* red = smem;            // [512][9] alias

    const int tid = threadIdx.x;
    const int h = blockIdx.y;
    const int rowBase = blockIdx.x * 512;
    const int p  = tid >> 6;
    const int dg = tid & 63;

    float tk = fminf(fmaxf(tk_arr[layer * 8 + h], 0.1f), 2.0f);
    float invtk = 1.0f / tk;
    for (int i = tid; i < 1024; i += 512) wvs[i] = wv[i];

    float wkr0[32], wkr1[32];
    #pragma unroll
    for (int j = 0; j < 32; ++j) {
        float2 w2 = *(const float2*)(wk + j * 128 + dg * 2);
        wkr0[j] = w2.x; wkr1[j] = w2.y;
    }

    float acc0[32], acc1[32];
    #pragma unroll
    for (int c = 0; c < 32; ++c) { acc0[c] = 0.f; acc1[c] = 0.f; }
    float se0 = 0.f, se1 = 0.f;

    const float* src = xm2 + (size_t)h * NP * 32 + (size_t)rowBase * 32;
    const int lr = tid >> 3, lc = (tid & 7) * 4;

    for (int tile = 0; tile < 8; ++tile) {
        __syncthreads();
        *(float4*)&xs[lr * 32 + lc] =
            *(const float4*)(src + (size_t)(tile * 64 + lr) * 32 + lc);
        __syncthreads();
        {
            float a0 = 0.f, a1 = 0.f, a2 = 0.f, a3 = 0.f;
            #pragma unroll
            for (int j = 0; j < 32; ++j) {
                float xv = xs[lr * 32 + j];
                float4 w4 = *(const float4*)&wvs[j * 32 + lc];
                a0 += xv * w4.x; a1 += xv * w4.y; a2 += xv * w4.z; a3 += xv * w4.w;
            }
            float4 o; o.x = a0; o.y = a1; o.z = a2; o.w = a3;
            *(float4*)&vs[lr * 32 + lc] = o;
        }
        __syncthreads();
        #pragma unroll 1
        for (int t = 0; t < 8; ++t) {
            int n = p * 8 + t;
            float l0 = 0.f, l1 = 0.f;
            #pragma unroll
            for (int j4 = 0; j4 < 8; ++j4) {
                float4 x4 = *(const float4*)&xs[n * 32 + j4 * 4];
                l0 += x4.x * wkr0[j4 * 4 + 0] + x4.y * wkr0[j4 * 4 + 1]
                    + x4.z * wkr0[j4 * 4 + 2] + x4.w * wkr0[j4 * 4 + 3];
                l1 += x4.x * wkr1[j4 * 4 + 0] + x4.y * wkr1[j4 * 4 + 1]
                    + x4.z * wkr1[j4 * 4 + 2] + x4.w * wkr1[j4 * 4 + 3];
            }
            float e0 = __expf(fminf(fmaxf(l0 * invtk, -60.f), 60.f));
            float e1 = __expf(fminf(fmaxf(l1 * invtk, -60.f), 60.f));
            se0 += e0; se1 += e1;
            #pragma unroll
            for (int cc = 0; cc < 8; ++cc) {
                float4 v4 = *(const float4*)&vs[n * 32 + cc * 4];
                acc0[cc*4+0] += e0 * v4.x; acc0[cc*4+1] += e0 * v4.y;
                acc0[cc*4+2] += e0 * v4.z; acc0[cc*4+3] += e0 * v4.w;
                acc1[cc*4+0] += e1 * v4.x; acc1[cc*4+1] += e1 * v4.y;
                acc1[cc*4+2] += e1 * v4.z; acc1[cc*4+3] += e1 * v4.w;
            }
        }
    }

    float* outp = partials + ((size_t)h * 64 + blockIdx.x) * 4224;
    #pragma unroll
    for (int cc = 0; cc < 8; ++cc) {
        __syncthreads();
        #pragma unroll
        for (int ci = 0; ci < 4; ++ci) {
            red[tid * 9 + ci]     = acc0[cc * 4 + ci];
            red[tid * 9 + 4 + ci] = acc1[cc * 4 + ci];
        }
        __syncthreads();
        int d = tid >> 2, ci = tid & 3;
        float s = 0.f;
        #pragma unroll
        for (int pp = 0; pp < 8; ++pp)
            s += red[(pp * 64 + (d >> 1)) * 9 + (d & 1) * 4 + ci];
        outp[d * 32 + cc * 4 + ci] = s;
    }
    __syncthreads();
    red[tid * 9 + 0] = se0;
    red[tid * 9 + 1] = se1;
    __syncthreads();
    if (tid < 128) {
        int d = tid;
        float s = 0.f;
        #pragma unroll
        for (int pp = 0; pp < 8; ++pp)
            s += red[(pp * 64 + (d >> 1)) * 9 + (d & 1)];
        outp[4096 + d] = s;
    }
}

__global__ __launch_bounds__(256) void kv_reduce_kernel(
    const float* __restrict__ partials, float* __restrict__ kvU,
    float* __restrict__ sumexp)
{
    int gid = blockIdx.x * 256 + threadIdx.x;
    if (gid >= 8 * 4224) return;
    int h = gid / 4224, idx = gid % 4224;
    const float* base = partials + (size_t)h * 64 * 4224 + idx;
    float s = 0.f;
    #pragma unroll 8
    for (int c = 0; c < 64; ++c) s += base[(size_t)c * 4224];
    if (idx < 4096) kvU[(size_t)h * 4096 + idx] = s;
    else sumexp[h * 128 + (idx - 4096)] = s;
}

// ---------------------------------------------------------------------------
// qkv3 — EXACT R9 version (fp32 float4 stores). R10's bf16-store variant
// tripled VGPR to 256 and spilled; reverted. Consumer (out_w1) converts
// fp32->bf16 during its A-stage instead.
// ---------------------------------------------------------------------------
__global__ __launch_bounds__(256) void qkv3_kernel(
    const float* __restrict__ xm2, const float* __restrict__ wq,
    const float* __restrict__ tq_arr,
    const float* __restrict__ kvU, const float* __restrict__ sumexp,
    float* __restrict__ outD, int layer)
{
    __shared__ __align__(16) float xsw[4096];
    __shared__ __align__(16) float wqs[4096];
    __shared__ __align__(16) float kvs[4096];
    __shared__ float ises[128];

    const int tid = threadIdx.x;
    const int h = blockIdx.y;
    const int rowBase = blockIdx.x * 128;
    const int rt = tid >> 4;
    const int dt = tid & 15;

    float tq = fminf(fmaxf(tq_arr[layer * 8 + h], 0.1f), 2.0f);
    float invtq = 1.0f / tq;

    if (tid < 128) ises[tid] = 1.0f / sumexp[h * 128 + tid];
    #pragma unroll
    for (int it = 0; it < 4; ++it) {
        int i4 = tid + it * 256;
        int k = i4 >> 5, c4 = i4 & 31;
        float4 v = *(const float4*)(wq + (size_t)k * 128 + c4 * 4);
        int c4s = c4 ^ ((c4 >> 1) & 7);
        *(float4*)&wqs[k * 128 + c4s * 4] = v;
    }
    {
        const float* kvsrc = kvU + (size_t)h * 4096;
        #pragma unroll
        for (int it = 0; it < 4; ++it) {
            int i4 = tid + it * 256;
            int d = i4 >> 3, c4 = i4 & 7;
            float4 v = *(const float4*)(kvsrc + (size_t)d * 32 + c4 * 4);
            int c4s = c4 ^ ((d >> 3) & 7);
            *(float4*)&kvs[d * 32 + c4s * 4] = v;
        }
    }
    {
        const float* src = xm2 + (size_t)h * NP * 32 + (size_t)rowBase * 32;
        #pragma unroll
        for (int it = 0; it < 4; ++it) {
            int s = tid + it * 256;
            int r = s >> 3, j4 = s & 7;
            float4 v = *(const float4*)(src + (size_t)r * 32 + j4 * 4);
            *(float4*)&xsw[r * 32 + ((j4 ^ ((r >> 3) & 7)) << 2)] = v;
        }
    }
    __syncthreads();

    const int swr = rt & 7;
    const int swd = dt & 7;

    float l[8][8];
    #pragma unroll
    for (int i = 0; i < 8; ++i)
        #pragma unroll
        for (int jd = 0; jd < 8; ++jd) l[i][jd] = 0.f;

    const int cA = (dt * 2)     ^ swd;
    const int cB = (dt * 2 + 1) ^ swd;
    #pragma unroll
    for (int j4 = 0; j4 < 8; ++j4) {
        float4 xv[8];
        #pragma unroll
        for (int i = 0; i < 8; ++i)
            xv[i] = *(const float4*)&xsw[(rt * 8 + i) * 32 + ((j4 ^ swr) << 2)];
        #pragma unroll
        for (int kk = 0; kk < 4; ++kk) {
            int k = j4 * 4 + kk;
            float4 wa = *(const float4*)&wqs[k * 128 + cA * 4];
            float4 wb = *(const float4*)&wqs[k * 128 + cB * 4];
            #pragma unroll
            for (int i = 0; i < 8; ++i) {
                float xx = (kk == 0) ? xv[i].x : (kk == 1) ? xv[i].y
                         : (kk == 2) ? xv[i].z : xv[i].w;
                l[i][0] += xx * wa.x; l[i][1] += xx * wa.y;
                l[i][2] += xx * wa.z; l[i][3] += xx * wa.w;
                l[i][4] += xx * wb.x; l[i][5] += xx * wb.y;
                l[i][6] += xx * wb.z; l[i][7] += xx * wb.w;
            }
        }
    }

    float isr[8];
    #pragma unroll
    for (int jd = 0; jd < 8; ++jd) isr[jd] = ises[dt * 8 + jd];
    #pragma unroll
    for (int i = 0; i < 8; ++i) {
        float m = l[i][0];
        #pragma unroll
        for (int jd = 1; jd < 8; ++jd) m = fmaxf(m, l[i][jd]);
        m = fmaxf(m, __shfl_xor(m, 1));
        m = fmaxf(m, __shfl_xor(m, 2));
        m = fmaxf(m, __shfl_xor(m, 4));
        m = fmaxf(m, __shfl_xor(m, 8));
        float s = 0.f;
        #pragma unroll
        for (int jd = 0; jd < 8; ++jd) {
            float e = __expf((l[i][jd] - m) * invtq);
            l[i][jd] = e;
            s += e;
        }
        s += __shfl_xor(s, 1);
        s += __shfl_xor(s, 2);
        s += __shfl_xor(s, 4);
        s += __shfl_xor(s, 8);
        float inv = 1.0f / s;
        #pragma unroll
        for (int jd = 0; jd < 8; ++jd) l[i][jd] *= inv * isr[jd];
    }

    const int b0 = dt & 1, b1 = (dt >> 1) & 1, b2 = (dt >> 2) & 1, b3 = (dt >> 3) & 1;
    #pragma unroll
    for (int chunk = 0; chunk < 4; ++chunk) {
        float o[8][8];
        #pragma unroll
        for (int i = 0; i < 8; ++i)
            #pragma unroll
            for (int c = 0; c < 8; ++c) o[i][c] = 0.f;
        const int kA = (chunk * 2)     ^ swd;
        const int kB = (chunk * 2 + 1) ^ swd;
        #pragma unroll
        for (int jd = 0; jd < 8; ++jd) {
            int d = dt * 8 + jd;
            float4 ka = *(const float4*)&kvs[d * 32 + kA * 4];
            float4 kb = *(const float4*)&kvs[d * 32 + kB * 4];
            #pragma unroll
            for (int i = 0; i < 8; ++i) {
                float p = l[i][jd];
                o[i][0] += p * ka.x; o[i][1] += p * ka.y;
                o[i][2] += p * ka.z; o[i][3] += p * ka.w;
                o[i][4] += p * kb.x; o[i][5] += p * kb.y;
                o[i][6] += p * kb.z; o[i][7] += p * kb.w;
            }
        }
        float t1[4][8];
        #pragma unroll
        for (int i = 0; i < 4; ++i)
            #pragma unroll
            for (int c = 0; c < 8; ++c) {
                float keep = b0 ? o[i + 4][c] : o[i][c];
                float send = b0 ? o[i][c] : o[i + 4][c];
                t1[i][c] = keep + __shfl_xor(send, 1);
            }
        float t2[2][8];
        #pragma unroll
        for (int i = 0; i < 2; ++i)
            #pragma unroll
            for (int c = 0; c < 8; ++c) {
                float keep = b1 ? t1[i + 2][c] : t1[i][c];
                float send = b1 ? t1[i][c] : t1[i + 2][c];
                t2[i][c] = keep + __shfl_xor(send, 2);
            }
        float t3[2][4];
        #pragma unroll
        for (int i = 0; i < 2; ++i)
            #pragma unroll
            for (int c = 0; c < 4; ++c) {
                float keep = b2 ? t2[i][c + 4] : t2[i][c];
                float send = b2 ? t2[i][c] : t2[i][c + 4];
                t3[i][c] = keep + __shfl_xor(send, 4);
            }
        float t4[4];
        #pragma unroll
        for (int c = 0; c < 4; ++c) {
            float keep = b3 ? t3[1][c] : t3[0][c];
            float send = b3 ? t3[0][c] : t3[1][c];
            t4[c] = keep + __shfl_xor(send, 8);
        }
        int row = rt * 8 + b0 * 4 + b1 * 2 + b3;
        float4 ov; ov.x = t4[0]; ov.y = t4[1]; ov.z = t4[2]; ov.w = t4[3];
        *(float4*)(outD + (size_t)(rowBase + row) * 256 + h * 32 + chunk * 8 + b2 * 4) = ov;
    }
}

// ---------------------------------------------------------------------------
// head: out[n] = LN(fx[n]; ln3) . head_w + head_b
// ---------------------------------------------------------------------------
__global__ __launch_bounds__(256) void head_kernel(
    const float* __restrict__ fx, const float* __restrict__ g, const float* __restrict__ b,
    const float* __restrict__ hw, const float* __restrict__ hb, float* __restrict__ out)
{
    int lane = threadIdx.x & 63;
    int row = blockIdx.x * 4 + (threadIdx.x >> 6);
    float4 v = *(const float4*)(fx + (size_t)row * 256 + lane * 4);
    float s1 = v.x + v.y + v.z + v.w;
    float s2 = v.x * v.x + v.y * v.y + v.z * v.z + v.w * v.w;
    #pragma unroll
    for (int m = 1; m < 64; m <<= 1) { s1 += __shfl_xor(s1, m); s2 += __shfl_xor(s2, m); }
    float mean = s1 * 0.00390625f;
    float rstd = rsqrtf(fmaxf(s2 * 0.00390625f - mean * mean, 0.f) + 1e-5f);
    float4 gg = *(const float4*)(g + lane * 4);
    float4 bb = *(const float4*)(b + lane * 4);
    float4 w4 = *(const float4*)(hw + lane * 4);
    float d = ((v.x - mean) * rstd * gg.x + bb.x) * w4.x
            + ((v.y - mean) * rstd * gg.y + bb.y) * w4.y
            + ((v.z - mean) * rstd * gg.z + bb.z) * w4.z
            + ((v.w - mean) * rstd * gg.w + bb.w) * w4.w;
    #pragma unroll
    for (int m = 1; m < 64; m <<= 1) d += __shfl_xor(d, m);
    if (lane == 0) out[row] = d + hb[0];
}

extern "C" void kernel_launch(void* const* d_in, const int* in_sizes, int n_in,
                              void* d_out, int out_size, void* d_ws, size_t ws_size,
                              hipStream_t stream)
{
    const float* x      = (const float*)d_in[0];
    const float* pre_w1 = (const float*)d_in[1];
    const float* pre_b1 = (const float*)d_in[2];
    const float* pre_w2 = (const float*)d_in[3];
    const float* pre_b2 = (const float*)d_in[4];
    const float* ph     = (const float*)d_in[5];
    const float* ln1_g  = (const float*)d_in[6];
    const float* ln1_b  = (const float*)d_in[7];
    const float* inp_w  = (const float*)d_in[8];
    const float* inp_b  = (const float*)d_in[9];
    const float* temp_q = (const float*)d_in[10];
    const float* temp_k = (const float*)d_in[11];
    const float* wq     = (const float*)d_in[12];
    const float* wk     = (const float*)d_in[13];
    const float* wv     = (const float*)d_in[14];
    const float* out_w1 = (const float*)d_in[15];
    const float* out_b1 = (const float*)d_in[16];
    const float* out_w2 = (const float*)d_in[17];
    const float* out_b2 = (const float*)d_in[18];
    const float* ln2_g  = (const float*)d_in[19];
    const float* ln2_b  = (const float*)d_in[20];
    const float* mlp_w1 = (const float*)d_in[21];
    const float* mlp_b1 = (const float*)d_in[22];
    const float* mlp_w2 = (const float*)d_in[23];
    const float* mlp_b2 = (const float*)d_in[24];
    const float* ln3_g  = (const float*)d_in[25];
    const float* ln3_b  = (const float*)d_in[26];
    const float* head_w = (const float*)d_in[27];
    const float* head_b = (const float*)d_in[28];
    float* out = (float*)d_out;

    // ws layout: fx f32 | C f32 (xm2) | fxh bf16 | ChH bf16 |
    //            scratch33 f32 (partials -> attn-Dt -> mlp-Dt; lifetimes
    //            sequential within a layer) | stats | kvU | se | c-vecs | wts
    float* fx = (float*)d_ws;
    float* C  = fx + (size_t)NP * 256;
    unsigned short* fxh = (unsigned short*)(C + (size_t)NP * 256);
    unsigned short* ChH = fxh + (size_t)NP * 256;
    float* scr = (float*)(ChH + (size_t)NP * 256);   // NP*256 f32
    float* st = scr + (size_t)NP * 256;
    float* kv = st + (size_t)NP * 8;
    float* se = kv + 8 * 4096;
    float* c1i = se + 8 * 128;
    float* c2i = c1i + 1280;
    float* c1m = c2i + 1280;
    float* c2m = c1m + 1280;
    unsigned short* wtPre = (unsigned short*)(c2m + 1280);
    unsigned short* wtL   = wtPre + 256 * 512;   // 25 x [256][256]

    unsigned short* wtIn = wtL;
    unsigned short* wtO1 = wtL +  5 * 65536;
    unsigned short* wtO2 = wtL + 10 * 65536;
    unsigned short* wtM1 = wtL + 15 * 65536;
    unsigned short* wtM2 = wtL + 20 * 65536;

    dim3 bt(256);

    // weight prep
    transpose_bf16_k<<<dim3(16, 8, 1), bt, 0, stream>>>(pre_w2, wtPre, 512);
    transpose_scale_bf16_k<<<dim3(8, 8, 5), bt, 0, stream>>>(inp_w,  ln1_g, wtIn, 256);
    transpose_bf16_k<<<dim3(8, 8, 5), bt, 0, stream>>>(out_w1, wtO1, 256);
    transpose_bf16_k<<<dim3(8, 8, 5), bt, 0, stream>>>(out_w2, wtO2, 256);
    transpose_scale_bf16_k<<<dim3(8, 8, 5), bt, 0, stream>>>(mlp_w1, ln2_g, wtM1, 256);
    transpose_bf16_k<<<dim3(8, 8, 5), bt, 0, stream>>>(mlp_w2, wtM2, 256);
    colsum_k<<<dim3(1, 1, 5), bt, 0, stream>>>(inp_w,  ln1_g, ln1_b, c2i, c1i);
    colsum_k<<<dim3(1, 1, 5), bt, 0, stream>>>(mlp_w1, ln2_g, ln2_b, c2m, c1m);

    dim3 gg(256, 2);

    // preprocess: fx/fxh = GELU(x@pre_w1+pre_b1)@pre_w2 + pre_b2 + ph (+stats)
    gemm_bf<true, false, false, false, false, true, false><<<gg, bt, 0, stream>>>(
        nullptr, nullptr, wtPre, pre_b2, ph, fx, fxh, nullptr, st,
        nullptr, nullptr, x, pre_w1, pre_b1, 512);

    for (int i = 0; i < 5; ++i) {
        // xm2 = perm( LN(fx;ln1) @ inp_w + inp_b )   [LN folded, bf16 A]
        gemm_bf<false, false, true, false, false, false, true><<<gg, bt, 0, stream>>>(
            fxh, nullptr, wtIn + (size_t)i * 65536, inp_b + i * 256, nullptr, C, nullptr,
            st, nullptr, c1i + i * 256, c2i + i * 256, nullptr, nullptr, nullptr, 256);
        // kv partials + reduce   (scr = partials)
        kv5_kernel<<<dim3(64, 8), dim3(512), 0, stream>>>(
            C, wk + (size_t)i * 4096, wv + (size_t)i * 1024, temp_k, scr, i);
        kv_reduce_kernel<<<dim3(132), bt, 0, stream>>>(scr, kv, se);
        // qkv -> scr (fp32 Dt)
        qkv3_kernel<<<dim3(256, 8), bt, 0, stream>>>(
            C, wq + (size_t)i * 4096, temp_q, kv, se, scr, i);
        // ChH = bf16( GELU(Dt @ out_w1 + out_b1) )   [fp32 A staging]
        gemm_bf<false, true, false, true, false, false, false><<<gg, bt, 0, stream>>>(
            nullptr, scr, wtO1 + (size_t)i * 65536, out_b1 + i * 256, nullptr,
            nullptr, ChH, nullptr, nullptr, nullptr, nullptr, nullptr, nullptr, nullptr, 256);
        // fx += Ch @ out_w2 + out_b2   (+stats, +fxh)   [bf16 A]
        gemm_bf<false, false, false, false, true, true, false><<<gg, bt, 0, stream>>>(
            ChH, nullptr, wtO2 + (size_t)i * 65536, out_b2 + i * 256, nullptr, fx, fxh,
            nullptr, st, nullptr, nullptr, nullptr, nullptr, nullptr, 256);
        // scr = fp32( GELU( LN(fx;ln2) @ mlp_w1 + mlp_b1 ) )  [LN folded, bf16 A]
        gemm_bf<false, false, true, true, false, false, false><<<gg, bt, 0, stream>>>(
            fxh, nullptr, wtM1 + (size_t)i * 65536, mlp_b1 + i * 256, nullptr, scr, nullptr,
            st, nullptr, c1m + i * 256, c2m + i * 256, nullptr, nullptr, nullptr, 256);
        // fx += Dt @ mlp_w2 + mlp_b2  (+stats, +fxh)   [fp32 A staging]
        gemm_bf<false, true, false, false, true, true, false><<<gg, bt, 0, stream>>>(
            nullptr, scr, wtM2 + (size_t)i * 65536, mlp_b2 + i * 256, nullptr, fx, fxh,
            nullptr, st, nullptr, nullptr, nullptr, nullptr, nullptr, 256);
    }
    head_kernel<<<dim3(NP / 4), bt, 0, stream>>>(fx, ln3_g, ln3_b, head_w, head_b, out);
}